// Round 13
// baseline (107.417 us; speedup 1.0000x reference)
//
#include <hip/hip_runtime.h>
#include <stdint.h>

#define N_SAMP 8192
#define D_DIM  512
#define P_DIM  1024
#define DT     0.1875f

typedef float f32x4 __attribute__((ext_vector_type(4)));
typedef float f32x2 __attribute__((ext_vector_type(2)));
typedef short bf16x8 __attribute__((ext_vector_type(8)));
typedef unsigned short u16;

__device__ __forceinline__ u16 f2bf(float x){
    unsigned int u = __float_as_uint(x);
    return (u16)((u + 0x7FFFu + ((u >> 16) & 1u)) >> 16);
}

__device__ __forceinline__ void load_lds16(const void* g, void* l){
    __builtin_amdgcn_global_load_lds(
        (const __attribute__((address_space(1))) void*)(uintptr_t)g,
        (__attribute__((address_space(3))) void*)(uint32_t)(uintptr_t)l,
        16, 0, 0);
}

// convert 8 f32 (two float4) -> one 16B bf16 granule in LDS
__device__ __forceinline__ void cvt_write(char* dst, float4 a, float4 b){
    u16 u[8] = {f2bf(a.x), f2bf(a.y), f2bf(a.z), f2bf(a.w),
                f2bf(b.x), f2bf(b.y), f2bf(b.z), f2bf(b.w)};
    *(uint4*)dst = *(const uint4*)u;              // static idx -> registers
}

// ---- prep: norms | transpose | gpart zero | counter zero ----
__global__ __launch_bounds__(256) void k_prep(const float* __restrict__ A,
                                              float* __restrict__ inv,
                                              u16* __restrict__ AnT,
                                              float* __restrict__ gpart,
                                              unsigned int* __restrict__ counter){
    const int tid = threadIdx.x;
    const int b = blockIdx.x;
    if (b < 32){                                  // column inverse norms of A
        __shared__ float red[8][32];
        const int p0 = b * 32;
        const int pl = tid & 31, dg = tid >> 5;
        float s = 0.f;
        #pragma unroll 8
        for (int i = 0; i < 64; ++i){
            float v = A[(size_t)(dg + 8 * i) * P_DIM + p0 + pl];
            s += v * v;
        }
        red[dg][pl] = s;
        __syncthreads();
        if (tid < 32){
            float t = 0.f;
            #pragma unroll
            for (int g = 0; g < 8; ++g) t += red[g][tid];
            inv[p0 + tid] = 1.0f / fmaxf(sqrtf(t), 1e-8f);
        }
        return;
    }
    if (b < 544){                                 // pure transpose tile 32x32
        __shared__ float tile[32][33];
        const int t = b - 32;
        const int p0 = (t & 31) * 32, d0 = (t >> 5) * 32;
        const int tx = tid & 31, ty = tid >> 5;   // 32 x 8
        #pragma unroll
        for (int j = 0; j < 4; ++j)
            tile[ty + j * 8][tx] = A[(size_t)(d0 + ty + j * 8) * P_DIM + p0 + tx];
        __syncthreads();
        #pragma unroll
        for (int j = 0; j < 4; ++j){
            int pp = ty + j * 8;
            AnT[(size_t)(p0 + pp) * D_DIM + d0 + tx] = f2bf(tile[tx][pp]);
        }
        return;
    }
    if (b < 576){                                 // zero gpart (32x256 float4)
        int i = (b - 544) * 256 + tid;
        ((float4*)gpart)[i] = (float4){0.f, 0.f, 0.f, 0.f};
        return;
    }
    if (tid == 0) *counter = 0u;                  // ticket reset (each call)
}

// ---- fused zconv + GEMM + ECF + last-block reduce ----
// A: z fp32 read directly, converted in-regs, ds_write to XOR-swizzled slot
// of the next buffer (reg-staged T14). B: global_load_lds from AnT (bf16).
__global__ __launch_bounds__(512, 4) void k_gemm_ecf(const float* __restrict__ z,
                                                     const u16* __restrict__ AnT,
                                                     const float* __restrict__ inv,
                                                     float* __restrict__ gpart,
                                                     unsigned int* __restrict__ counter,
                                                     float* __restrict__ out){
    __shared__ uint4 smem4[4096];                 // 64 KiB: 2 x (A 16K + B 16K)
    const int tid = threadIdx.x;
    const int swz = (blockIdx.x & 7) * 64 + (blockIdx.x >> 3);  // XCD swizzle
    const int bm = swz >> 3, bn = swz & 7;
    const int m0 = bm << 7, n0 = bn << 7;
    const int w = tid >> 6, lane = tid & 63;      // 8 waves
    const int r = lane & 15, kg = lane >> 4;
    const int wm = (w >> 2) << 6;                 // row half
    const int wn = (w & 3) << 5;                  // col quarter

    // A reg-staging: thread t -> row arow (0..127), granule pair agrp,agrp+1
    const int arow = tid >> 2;
    const int agrp = (tid & 3) << 1;
    const int sA = arow & 7;                      // row's XOR key
    const float4* gz = (const float4*)z + (size_t)(m0 + arow) * 128 + agrp * 2;
    const int wofs0 = arow * 128 + ((agrp     ^ sA) << 4);
    const int wofs1 = arow * 128 + (((agrp+1) ^ sA) << 4);

    // B staging via global_load_lds: pre-swizzled source, linear LDS dest
    const int srow = tid >> 3;                    // 0..63
    const int gsw  = ((tid & 7) ^ (srow & 7)) << 3;
    const u16* gB = AnT + (size_t)(n0 + srow) * D_DIM + gsw;
    char* lbase = (char*)smem4 + w * 1024;        // wave-uniform B dest base

    f32x4 acc[4][2] = {};

    // prologue: tile 0 -> buf0 (A converted inline, B async)
    {
        float4 f0 = gz[0], f1 = gz[1], f2 = gz[2], f3 = gz[3];
        char* A0 = (char*)smem4;
        cvt_write(A0 + wofs0, f0, f1);
        cvt_write(A0 + wofs1, f2, f3);
        #pragma unroll
        for (int h = 0; h < 2; ++h)
            load_lds16(gB + (size_t)h * 64 * D_DIM, lbase + 16384 + h * 8192);
    }

    for (int kt = 0; kt < 8; ++kt){
        const int cur = kt & 1;
        __syncthreads();                          // cur tile ready (ds_write + B drained)
        float4 f0, f1, f2, f3;
        if (kt < 7){                              // issue next-tile loads early
            char* la = lbase + ((kt + 1) & 1) * 32768;   // WAVE-UNIFORM base (R12 bug: missing w*1024)
            #pragma unroll
            for (int h = 0; h < 2; ++h)
                load_lds16(gB + (size_t)h * 64 * D_DIM + (kt + 1) * 64,
                           la + 16384 + h * 8192);
            f0 = gz[(kt + 1) * 16 + 0]; f1 = gz[(kt + 1) * 16 + 1];
            f2 = gz[(kt + 1) * 16 + 2]; f3 = gz[(kt + 1) * 16 + 3];
        }
        const u16* Ab = (const u16*)smem4 + cur * 16384;
        const u16* Bb = Ab + 8192;
        #pragma unroll
        for (int ks = 0; ks < 2; ++ks){
            bf16x8 af[4], bfr[2];
            #pragma unroll
            for (int i = 0; i < 4; ++i)
                af[i] = *(const bf16x8*)&Ab[(wm + i * 16 + r) * 64 +
                                            (((ks * 4 + kg) ^ (r & 7)) << 3)];
            #pragma unroll
            for (int j = 0; j < 2; ++j)
                bfr[j] = *(const bf16x8*)&Bb[(wn + j * 16 + r) * 64 +
                                             (((ks * 4 + kg) ^ (r & 7)) << 3)];
            #pragma unroll
            for (int i = 0; i < 4; ++i)
                #pragma unroll
                for (int j = 0; j < 2; ++j)
                    acc[i][j] = __builtin_amdgcn_mfma_f32_16x16x32_bf16(
                        af[i], bfr[j], acc[i][j], 0, 0, 0);
        }
        if (kt < 7){                              // convert + write after MFMAs
            char* An = (char*)smem4 + ((kt + 1) & 1) * 32768;
            cvt_write(An + wofs0, f0, f1);
            cvt_write(An + wofs1, f2, f3);
        }
    }

    // ---- epilogue: packed (cos,sin) Chebyshev recurrence, reduce rows ----
    __syncthreads();
    float* epil = (float*)smem4;                  // [8 waves][32 j][32 cols]
    #pragma unroll
    for (int jn = 0; jn < 2; ++jn){
        const float sc = inv[n0 + wn + jn * 16 + r] * DT;
        f32x2 sum[16];
        #pragma unroll
        for (int k = 0; k < 16; ++k) sum[k] = (f32x2){0.f, 0.f};
        #pragma unroll
        for (int i = 0; i < 4; ++i){
            #pragma unroll
            for (int q = 0; q < 4; ++q){
                float x = acc[i][jn][q] * sc;
                float c1 = __cosf(x), s1 = __sinf(x);
                float tc = c1 + c1;
                f32x2 prev = {1.f, 0.f};
                f32x2 curv = {c1, s1};
                sum[0] += curv;
                #pragma unroll
                for (int k = 2; k <= 16; ++k){
                    f32x2 nxt = tc * curv - prev;
                    sum[k - 1] += nxt;
                    prev = curv; curv = nxt;
                }
            }
        }
        #pragma unroll
        for (int k = 0; k < 16; ++k){
            f32x2 o;
            o.x = __shfl_xor(sum[k].x, 16); o.y = __shfl_xor(sum[k].y, 16);
            sum[k] += o;
            o.x = __shfl_xor(sum[k].x, 32); o.y = __shfl_xor(sum[k].y, 32);
            sum[k] += o;
        }
        if (lane < 16){
            const int cl = jn * 16 + lane;
            #pragma unroll
            for (int k = 0; k < 16; ++k){
                epil[(w * 32 + k)      * 32 + cl] = sum[k].x;
                epil[(w * 32 + 16 + k) * 32 + cl] = sum[k].y;
            }
        }
    }
    __syncthreads();
    for (int f0i = 0; f0i < 4096; f0i += 512){    // fold row-halves, atomic
        int f = f0i + tid;
        int cl = f & 127, j = f >> 7;
        int whi = cl >> 5, cll = cl & 31;
        float v = epil[((whi    ) * 32 + j) * 32 + cll] +
                  epil[((whi + 4) * 32 + j) * 32 + cll];
        atomicAdd(&gpart[j * P_DIM + n0 + cl], v);
    }

    // ---- last block: weighted reduce of gpart -> out ----
    __threadfence();
    __shared__ unsigned int sticket;
    if (tid == 0) sticket = atomicAdd(counter, 1u);
    __syncthreads();
    if (sticket == 511u){
        __threadfence();
        float part = 0.f;
        for (int i = tid; i < 32768; i += 512){
            const int j = i >> 10;
            const int k = (j & 15) + 1;
            float tk = (float)k * DT;
            float phik = expf(-0.5f * tk * tk);
            float wk = ((k == 16) ? DT : 2.f * DT) * phik;
            float mean = gpart[i] * (1.f / (float)N_SAMP);
            float diff = (j < 16) ? (mean - phik) : mean;
            part += diff * diff * wk;
        }
        #pragma unroll
        for (int o = 32; o > 0; o >>= 1) part += __shfl_xor(part, o);
        float* red = (float*)smem4;
        __syncthreads();
        if (lane == 0) red[w] = part;
        __syncthreads();
        if (tid == 0){
            float s = 0.f;
            #pragma unroll
            for (int i = 0; i < 8; ++i) s += red[i];
            out[0] = s * ((float)N_SAMP / (float)P_DIM);
        }
    }
}

extern "C" void kernel_launch(void* const* d_in, const int* in_sizes, int n_in,
                              void* d_out, int out_size, void* d_ws, size_t ws_size,
                              hipStream_t stream){
    const float* z = (const float*)d_in[0];
    const float* A = (const float*)d_in[1];
    char* ws = (char*)d_ws;
    float* inv        = (float*)(ws);             // 4 KiB
    unsigned int* cnt = (unsigned int*)(ws + 4096);
    float* gpart      = (float*)(ws + 8192);      // 128 KiB [32][1024] f32
    u16*   AnT        = (u16*)  (ws + 139264);    // 1 MiB  [1024][512] bf16
    float* out        = (float*)d_out;

    hipLaunchKernelGGL(k_prep,     dim3(577), dim3(256), 0, stream,
                       A, inv, AnT, gpart, cnt);
    hipLaunchKernelGGL(k_gemm_ecf, dim3(512), dim3(512), 0, stream,
                       z, AnT, inv, gpart, cnt, out);
}